// Round 1
// baseline (81.274 us; speedup 1.0000x reference)
//
#include <hip/hip_runtime.h>

#define H       256
#define NF      2
#define CHUNKS  16
#define ROWS    (H / CHUNKS)   // 16 rows of W2 per block

// ---------------------------------------------------------------------------
// Kernel 1: collapse the linear MADE net into 4 scalars per flow.
//   a_s = u @ W2 @ w3s,  a_l = u @ W2 @ w3l   (u = W1[f,0,:])
//   c_s_part = b1 @ W2 @ w3s (+ b2 @ w3s on chunk 0), same for c_l.
// Each block handles 16 rows of W2 (coalesced: thread j reads W2[f,k,j]),
// reduces, writes a 4-float partial to ws[(f*CHUNKS+c)*4 + {0..3}].
// ---------------------------------------------------------------------------
__global__ __launch_bounds__(256)
void precompute_kernel(const float* __restrict__ W1,
                       const float* __restrict__ b1,
                       const float* __restrict__ W2,
                       const float* __restrict__ b2,
                       const float* __restrict__ W3,
                       float* __restrict__ ws) {
    const int f = blockIdx.x / CHUNKS;
    const int c = blockIdx.x % CHUNKS;
    const int j = threadIdx.x;

    __shared__ float lu[ROWS], lb[ROWS];
    if (j < ROWS) {
        const int k = c * ROWS + j;
        lu[j] = W1[f * 2 * H + k];   // W1[f, 0, k]
        lb[j] = b1[f * H + k];
    }
    __syncthreads();

    const float w3s = W3[f * H * 4 + j * 4 + 2];
    const float w3l = W3[f * H * 4 + j * 4 + 3];

    float t = 0.f, tb = 0.f;
    const float* W2col = W2 + (size_t)f * H * H + (size_t)(c * ROWS) * H + j;
#pragma unroll
    for (int r = 0; r < ROWS; ++r) {
        const float w = W2col[r * H];
        t  += lu[r] * w;
        tb += lb[r] * w;
    }

    float a0 = t  * w3s;   // a_s partial
    float a1 = t  * w3l;   // a_l partial
    float a2 = tb * w3s;   // c_s partial
    float a3 = tb * w3l;   // c_l partial
    if (c == 0) {          // fold the b2 contribution in exactly once
        const float bb = b2[f * H + j];
        a2 += bb * w3s;
        a3 += bb * w3l;
    }

    __shared__ float red[4][256];
    red[0][j] = a0; red[1][j] = a1; red[2][j] = a2; red[3][j] = a3;
    __syncthreads();
#pragma unroll
    for (int s = 128; s > 0; s >>= 1) {
        if (j < s) {
            red[0][j] += red[0][j + s];
            red[1][j] += red[1][j + s];
            red[2][j] += red[2][j + s];
            red[3][j] += red[3][j + s];
        }
        __syncthreads();
    }
    if (j == 0) {
        float* o = ws + (size_t)(f * CHUNKS + c) * 4;
        o[0] = red[0][0]; o[1] = red[1][0]; o[2] = red[2][0]; o[3] = red[3][0];
    }
}

// ---------------------------------------------------------------------------
// Kernel 2: reparameterize + 2 collapsed MAF flows, fully elementwise.
// ---------------------------------------------------------------------------
__global__ __launch_bounds__(256)
void maf_kernel(const float* __restrict__ zm,
                const float* __restrict__ zlv,
                const float* __restrict__ eps,
                const float* __restrict__ b3,
                const float* __restrict__ ws,
                float* __restrict__ out,
                int n) {
    __shared__ float part[NF * CHUNKS * 4];   // 128 floats
    const int t = threadIdx.x;
    if (t < NF * CHUNKS * 4) part[t] = ws[t];
    __syncthreads();

    float a_s[NF], a_l[NF], c_s[NF], c_l[NF], e0[NF], s0[NF];
#pragma unroll
    for (int f = 0; f < NF; ++f) {
        float as = 0.f, al = 0.f, cs = 0.f, cl = 0.f;
#pragma unroll
        for (int c = 0; c < CHUNKS; ++c) {
            const float* p = &part[(f * CHUNKS + c) * 4];
            as += p[0]; al += p[1]; cs += p[2]; cl += p[3];
        }
        a_s[f] = as;
        a_l[f] = al;
        c_s[f] = cs + b3[f * 4 + 2];
        c_l[f] = cl + b3[f * 4 + 3];
        s0[f]  = b3[f * 4 + 0];
        e0[f]  = expf(b3[f * 4 + 1]);
    }

    const int i = blockIdx.x * blockDim.x + t;
    if (i >= n) return;

    const float2 m = ((const float2*)zm)[i];
    const float2 v = ((const float2*)zlv)[i];
    const float2 e = ((const float2*)eps)[i];

    float z0 = m.x + expf(0.5f * v.x) * e.x;
    float z1 = m.y + expf(0.5f * v.y) * e.y;

#pragma unroll
    for (int f = 0; f < NF; ++f) {
        const float y0 = z0 * e0[f] + s0[f];
        const float y1 = z1 * expf(a_l[f] * y0 + c_l[f]) + (a_s[f] * y0 + c_s[f]);
        z0 = y0;
        z1 = y1;
    }
    ((float2*)out)[i] = make_float2(z0, z1);
}

extern "C" void kernel_launch(void* const* d_in, const int* in_sizes, int n_in,
                              void* d_out, int out_size, void* d_ws, size_t ws_size,
                              hipStream_t stream) {
    const float* zm  = (const float*)d_in[0];
    const float* zlv = (const float*)d_in[1];
    const float* eps = (const float*)d_in[2];
    const float* W1  = (const float*)d_in[3];
    const float* b1  = (const float*)d_in[4];
    const float* W2  = (const float*)d_in[5];
    const float* b2  = (const float*)d_in[6];
    const float* W3  = (const float*)d_in[7];
    const float* b3  = (const float*)d_in[8];
    float* out = (float*)d_out;
    float* ws  = (float*)d_ws;

    const int n = in_sizes[0] / 2;   // number of samples (B)

    precompute_kernel<<<NF * CHUNKS, 256, 0, stream>>>(W1, b1, W2, b2, W3, ws);
    maf_kernel<<<(n + 255) / 256, 256, 0, stream>>>(zm, zlv, eps, b3, ws, out, n);
}

// Round 2
// 81.235 us; speedup vs baseline: 1.0005x; 1.0005x over previous
//
#include <hip/hip_runtime.h>

#define H       256
#define NF      2
#define CHUNKS  16
#define ROWS    (H / CHUNKS)   // 16 rows of W2 per block

// ---------------------------------------------------------------------------
// Kernel 1: collapse the linear MADE net into 4 scalars per flow.
// The masked MADE with activation=None is linear; masks kill everything except
// a rank-1 dependence on y0 for dim-1's outputs and pure-bias for dim-0's.
//   a_s = u @ W2 @ w3s,  a_l = u @ W2 @ w3l     (u = W1[f,0,:])
//   c_* = (b1 @ W2 + b2) @ w3* (+ b3 later)
// 32 blocks; block (f,c) handles 16 rows of W2, coalesced across threads.
// Partials to ws[(f*CHUNKS+c)*4 + {0..3}].
// ---------------------------------------------------------------------------
__global__ __launch_bounds__(256)
void precompute_kernel(const float* __restrict__ W1,
                       const float* __restrict__ b1,
                       const float* __restrict__ W2,
                       const float* __restrict__ b2,
                       const float* __restrict__ W3,
                       float* __restrict__ ws) {
    const int f = blockIdx.x / CHUNKS;
    const int c = blockIdx.x % CHUNKS;
    const int j = threadIdx.x;

    __shared__ float lu[ROWS], lb[ROWS];
    if (j < ROWS) {
        const int k = c * ROWS + j;
        lu[j] = W1[f * 2 * H + k];   // W1[f, 0, k]
        lb[j] = b1[f * H + k];
    }
    __syncthreads();

    const float w3s = W3[f * H * 4 + j * 4 + 2];
    const float w3l = W3[f * H * 4 + j * 4 + 3];

    float t = 0.f, tb = 0.f;
    const float* W2col = W2 + (size_t)f * H * H + (size_t)(c * ROWS) * H + j;
#pragma unroll
    for (int r = 0; r < ROWS; ++r) {
        const float w = W2col[r * H];
        t  += lu[r] * w;
        tb += lb[r] * w;
    }

    float a0 = t  * w3s;   // a_s partial
    float a1 = t  * w3l;   // a_l partial
    float a2 = tb * w3s;   // c_s partial
    float a3 = tb * w3l;   // c_l partial
    if (c == 0) {          // fold the b2 contribution in exactly once
        const float bb = b2[f * H + j];
        a2 += bb * w3s;
        a3 += bb * w3l;
    }

    __shared__ float red[4][256];
    red[0][j] = a0; red[1][j] = a1; red[2][j] = a2; red[3][j] = a3;
    __syncthreads();
#pragma unroll
    for (int s = 128; s > 0; s >>= 1) {
        if (j < s) {
            red[0][j] += red[0][j + s];
            red[1][j] += red[1][j + s];
            red[2][j] += red[2][j + s];
            red[3][j] += red[3][j + s];
        }
        __syncthreads();
    }
    if (j == 0) {
        float* o = ws + (size_t)(f * CHUNKS + c) * 4;
        o[0] = red[0][0]; o[1] = red[1][0]; o[2] = red[2][0]; o[3] = red[3][0];
    }
}

// ---------------------------------------------------------------------------
// Kernel 2: reparameterize + 2 collapsed MAF flows, elementwise.
// float4 path: each thread handles 2 samples (16 B/lane loads & store).
// ---------------------------------------------------------------------------
__global__ __launch_bounds__(256)
void maf_kernel(const float4* __restrict__ zm,
                const float4* __restrict__ zlv,
                const float4* __restrict__ eps,
                const float* __restrict__ b3,
                const float* __restrict__ ws,
                float4* __restrict__ out,
                int n4) {
    __shared__ float part[NF * CHUNKS * 4];   // 128 partials
    __shared__ float fin[NF * 4];             // a_s, a_l, c_s, c_l per flow
    const int t = threadIdx.x;
    if (t < NF * CHUNKS * 4) part[t] = ws[t];
    __syncthreads();
    if (t < NF * 4) {
        const int f = t >> 2, q = t & 3;
        float s = 0.f;
#pragma unroll
        for (int c = 0; c < CHUNKS; ++c) s += part[(f * CHUNKS + c) * 4 + q];
        fin[t] = s;
    }
    __syncthreads();

    float a_s[NF], a_l[NF], c_s[NF], c_l[NF], e0[NF], s0[NF];
#pragma unroll
    for (int f = 0; f < NF; ++f) {
        a_s[f] = fin[f * 4 + 0];
        a_l[f] = fin[f * 4 + 1];
        c_s[f] = fin[f * 4 + 2] + b3[f * 4 + 2];
        c_l[f] = fin[f * 4 + 3] + b3[f * 4 + 3];
        s0[f]  = b3[f * 4 + 0];
        e0[f]  = expf(b3[f * 4 + 1]);
    }

    const int i = blockIdx.x * blockDim.x + t;
    if (i >= n4) return;

    const float4 m = zm[i];
    const float4 v = zlv[i];
    const float4 e = eps[i];

    // sample A (x,y), sample B (z,w)
    float za0 = m.x + expf(0.5f * v.x) * e.x;
    float za1 = m.y + expf(0.5f * v.y) * e.y;
    float zb0 = m.z + expf(0.5f * v.z) * e.z;
    float zb1 = m.w + expf(0.5f * v.w) * e.w;

#pragma unroll
    for (int f = 0; f < NF; ++f) {
        const float ya0 = za0 * e0[f] + s0[f];
        const float yb0 = zb0 * e0[f] + s0[f];
        za1 = za1 * expf(a_l[f] * ya0 + c_l[f]) + (a_s[f] * ya0 + c_s[f]);
        zb1 = zb1 * expf(a_l[f] * yb0 + c_l[f]) + (a_s[f] * yb0 + c_s[f]);
        za0 = ya0;
        zb0 = yb0;
    }
    out[i] = make_float4(za0, za1, zb0, zb1);
}

extern "C" void kernel_launch(void* const* d_in, const int* in_sizes, int n_in,
                              void* d_out, int out_size, void* d_ws, size_t ws_size,
                              hipStream_t stream) {
    const float* zm  = (const float*)d_in[0];
    const float* zlv = (const float*)d_in[1];
    const float* eps = (const float*)d_in[2];
    const float* W1  = (const float*)d_in[3];
    const float* b1  = (const float*)d_in[4];
    const float* W2  = (const float*)d_in[5];
    const float* b2  = (const float*)d_in[6];
    const float* W3  = (const float*)d_in[7];
    const float* b3  = (const float*)d_in[8];
    float* out = (float*)d_out;
    float* ws  = (float*)d_ws;

    const int n4 = in_sizes[0] / 4;   // number of float4s (= 2 samples each)

    precompute_kernel<<<NF * CHUNKS, 256, 0, stream>>>(W1, b1, W2, b2, W3, ws);
    maf_kernel<<<(n4 + 255) / 256, 256, 0, stream>>>(
        (const float4*)zm, (const float4*)zlv, (const float4*)eps, b3, ws,
        (float4*)out, n4);
}